// Round 5
// baseline (215.951 us; speedup 1.0000x reference)
//
#include <hip/hip_runtime.h>
#include <cfloat>
#include <cmath>

#define NHEADS 3
#define HIDC   64
#define HCC    192   // NHEADS*HIDC
#define EMBC   128
#define WCOLS  384   // 2*HCC (Wl rows ++ Wr rows)
#define CAP    1280  // edge slots per 64-dst bucket (mean 1024, +8 sigma)
#define SCH    4096  // edges per scatter block. Keep blocks (E/SCH=196) <= 256 CUs
                     // (R1: 391 blocks -> serial scatter pairs on some CUs, regressed).
#define SPLIT  2     // edge blocks per bucket (partial facc + finalize)

typedef unsigned short bhalf;
typedef __fp16 half_t;
typedef __attribute__((ext_vector_type(2))) __fp16 h2;
typedef __attribute__((ext_vector_type(8))) short bf16x8;
typedef __attribute__((ext_vector_type(4))) float f32x4;
typedef __attribute__((ext_vector_type(2))) float f32x2;

__device__ __forceinline__ unsigned f2bf(float f) {   // RNE fp32 -> bf16 bits
  unsigned u = __float_as_uint(f);
  return (u + 0x7FFFu + ((u >> 16) & 1u)) >> 16;
}
__device__ __forceinline__ unsigned h2bits(h2 v) {
  union { h2 h; unsigned u; } cv; cv.h = v; return cv.u;
}

// ---- prep: Wb bf16[384][128]; bfl[384]=bl++br; weh=pk16(16*We);
//            atth=pk16(att/16); cur[] bucket cursors; sumexp=0.
// 16x fp8 scale trick: store fp8 of 16*x (leakyrelu positively homogeneous;
// 1/16 folded into atth).
__global__ __launch_bounds__(256) void prep_kernel(
    const float* __restrict__ Wl, const float* __restrict__ Wr,
    const float* __restrict__ bl, const float* __restrict__ br,
    const float* __restrict__ We, const float* __restrict__ att,
    bhalf* __restrict__ Wb, float* __restrict__ bfl,
    unsigned* __restrict__ weh, unsigned* __restrict__ atth,
    unsigned* __restrict__ cur, float* __restrict__ sumexp, int NB)
{
  const int BASE = WCOLS * EMBC;
  int gt = blockIdx.x * 256 + threadIdx.x;
  if (gt < BASE) {                                      // Wb (bf16 RNE)
    int c = gt >> 7, k = gt & 127;
    float v = (c < HCC) ? Wl[c * EMBC + k] : Wr[(c - HCC) * EMBC + k];
    Wb[gt] = (bhalf)f2bf(v);
  } else if (gt < BASE + 384) {                         // bfl = bl++br
    int c = gt - BASE;
    bfl[c] = (c < HCC) ? bl[c] : br[c - HCC];
  } else if (gt < BASE + 480) {                         // weh (96 x fp16x2 of 16*We)
    int i = gt - BASE - 384;
    weh[i] = h2bits(__builtin_amdgcn_cvt_pkrtz(16.f * We[2 * i], 16.f * We[2 * i + 1]));
  } else if (gt < BASE + 576) {                         // atth (att/16)
    int i = gt - BASE - 480;
    atth[i] = h2bits(__builtin_amdgcn_cvt_pkrtz(att[2 * i] * (1.f / 16.f),
                                                att[2 * i + 1] * (1.f / 16.f)));
  } else if (gt < BASE + 576 + NB) {                    // bucket append cursors
    int b = gt - BASE - 576;
    cur[b * 16] = (unsigned)(b * CAP);                  // 64B-padded counters
  } else if (gt == BASE + 576 + NB) {
    *sumexp = 0.f;
  }
}

// One GEMM pass over 6 of the 12 column-tiles. Two-pass split keeps live
// accumulator at 24 AGPR (vs 48) so the GEMM branch fits the 85-reg cap of
// launch_bounds(256,6) WITHOUT spilling (R3's failure mode: 12-tile acc at
// cap 85 -> scratch, +37MB hbm). All register-array indices compile-time
// (template P, scalar pjp0/1/2) — dynamic-indexed reg arrays go to scratch.
template<int P>
__device__ __forceinline__ void gemm_pass(
    bhalf* Ws, const bhalf* __restrict__ Wb, const float* __restrict__ bfl,
    const float* __restrict__ Wout, unsigned char* xo, int N,
    int tid, int m, int q, int half, int node, const bf16x8* pfrag,
    float& pjp0, float& pjp1, float& pjp2)
{
  f32x4 acc[6];
  #pragma unroll
  for (int t = 0; t < 6; ++t) acc[t] = (f32x4){0.f, 0.f, 0.f, 0.f};

  #pragma unroll
  for (int kh = 0; kh < 2; ++kh) {
    __syncthreads();
    for (int f = tid; f < 192 * 8; f += 256) {     // stage 64-k half (L2-hot)
      int cc = f >> 3, s = f & 7;
      uint4 v = *(const uint4*)(Wb + (size_t)(half * HCC + cc) * EMBC + kh * 64 + s * 8);
      *(uint4*)(Ws + cc * 64 + ((s ^ (cc & 7)) * 8)) = v;
    }
    __syncthreads();
    #pragma unroll
    for (int kt2 = 0; kt2 < 2; ++kt2) {
      #pragma unroll
      for (int t = 0; t < 6; ++t) {
        bf16x8 wf = *(const bf16x8*)(Ws + ((P * 6 + t) * 16 + m) * 64 +
                                     (((kt2 << 2) + q) ^ (m & 7)) * 8);
        acc[t] = __builtin_amdgcn_mfma_f32_16x16x32_bf16(wf, pfrag[kh * 2 + kt2],
                                                         acc[t], 0, 0, 0);
      }
    }
  }

  // epilogue for tiles P*6 .. P*6+5
  #pragma unroll
  for (int t = 0; t < 6; ++t) {
    const int tt = P * 6 + t;
    int col = tt * 16 + q * 4;
    float4 b = *(const float4*)(bfl + half * HCC + col);
    float r0 = acc[t][0] + b.x;
    float r1 = acc[t][1] + b.y;
    float r2 = acc[t][2] + b.z;
    float r3 = acc[t][3] + b.w;
    if (half == 0) {
      float4 wo = *(const float4*)(Wout + (tt & 3) * 16 + q * 4);  // L1-hot
      float d = r0 * wo.x + r1 * wo.y + r2 * wo.z + r3 * wo.w;
      if ((tt >> 2) == 0)      pjp0 += d;
      else if ((tt >> 2) == 1) pjp1 += d;
      else                     pjp2 += d;
    }
    if (node < N) {
      int p = 0;
      p = __builtin_amdgcn_cvt_pk_fp8_f32(16.f * r0, 16.f * r1, p, false);
      p = __builtin_amdgcn_cvt_pk_fp8_f32(16.f * r2, 16.f * r3, p, true);
      *(unsigned*)(xo + (size_t)node * HCC + col) = (unsigned)p;
    }
  }
}

// ---- FUSED: edge scatter (blocks < NSC, FIRST so they overlap) + MFMA GEMM.
// gemm: operand swap mfma(Wfrag,pefrag) -> D col=node, row(q*4+reg)=wcol;
// 4 consecutive wcols/lane -> fp8(16x) pack -> direct dword store.
// pj computed IN-EPILOGUE from (acc+bias)·Wout (exact fp32 value path).
// CONFIG LEDGER (measured):
//   R0: LDS-W 12-tile + bounds(256,4) = 53.5us (1.47TB/s, occ 33%).
//   R2: direct-global W = 71.6us (bank conflicts NOT critical; VMEM latency was).
//   R3: bounds(256,6) with 12-tile acc = spill (VGPR 52->40, +37MB scratch).
//   R5 (this): two-pass 6-tile acc + bounds(256,6) — occupancy 4->6 blocks/CU
//   targeting the measured latency wall (all pipes <10% busy, HBM 16%).
// scatter: rank-reuse — phase-1 histogram atomicAdd return IS the rank.
__global__ __launch_bounds__(256, 6) void gemmscatter_kernel(
    const float* __restrict__ pe, const bhalf* __restrict__ Wb,
    const float* __restrict__ bfl, const float* __restrict__ Wout,
    unsigned char* __restrict__ xl8, unsigned char* __restrict__ xr8,
    float* __restrict__ pj, int N,
    const int* __restrict__ ei, const float* __restrict__ ea,
    uint2* __restrict__ eb, unsigned* __restrict__ cur, int E, int NSC)
{
  __shared__ union {
    bhalf Ws[192 * 64];                        // 24576 B gemm W tile (6/CU = 147KB)
    struct { unsigned lh[800]; unsigned lbase[800]; } s;   // scatter hists
  } sm;
  const int tid = threadIdx.x;

  if ((int)blockIdx.x < NSC) {   // ============ SCATTER (dispatched first) ============
    const int base = blockIdx.x * SCH;
    for (int i = tid; i < 800; i += 256) sm.s.lh[i] = 0;
    __syncthreads();
    unsigned packed[SCH / 256];     // dst(16b) | rank(<<16), fully in VGPRs
    #pragma unroll
    for (int i = 0; i < SCH / 256; ++i) {
      int e = base + i * 256 + tid;
      packed[i] = 0xFFFFFFFFu;
      if (e < E) {
        unsigned dst = (unsigned)ei[E + e];
        unsigned r = atomicAdd(&sm.s.lh[dst >> 6], 1u);   // rank in bin
        packed[i] = dst | (r << 16);
      }
    }
    __syncthreads();
    for (int i = tid; i < 800; i += 256) {      // reserve global ranges
      unsigned c = sm.s.lh[i];
      sm.s.lbase[i] = c ? atomicAdd(&cur[i * 16], c) : 0u;
    }
    __syncthreads();
    #pragma unroll
    for (int i = 0; i < SCH / 256; ++i) {
      int e = base + i * 256 + tid;
      if (e < E) {
        unsigned pk = packed[i];
        unsigned dst = pk & 0xFFFFu;
        unsigned slot = sm.s.lbase[dst >> 6] + (pk >> 16);
        uint2 rec;
        rec.x = (unsigned)ei[e] | (dst << 16);   // N < 65536
        rec.y = __float_as_uint(ea[e]);
        eb[slot] = rec;
      }
    }
  } else {   // ================= GEMM =================
    const int bid  = blockIdx.x - NSC;
    const int w    = tid >> 6;
    const int lane = tid & 63;
    const int m    = lane & 15;
    const int q    = lane >> 4;
    const int nb   = bid >> 1;
    const int half = bid & 1;
    const int node = nb * 64 + w * 16 + m;
    const size_t prow = (size_t)(node < N ? node : N - 1) * EMBC;

    bf16x8 pfrag[4];
    #pragma unroll
    for (int kt = 0; kt < 4; ++kt) {
      const float* p = pe + prow + kt * 32 + q * 8;
      float4 x = *(const float4*)p;
      float4 y = *(const float4*)(p + 4);
      union { bf16x8 v; unsigned u[4]; } uu;   // trunc-pack pe -> bf16
      uu.u[0] = (__float_as_uint(x.x) >> 16) | (__float_as_uint(x.y) & 0xFFFF0000u);
      uu.u[1] = (__float_as_uint(x.z) >> 16) | (__float_as_uint(x.w) & 0xFFFF0000u);
      uu.u[2] = (__float_as_uint(y.x) >> 16) | (__float_as_uint(y.y) & 0xFFFF0000u);
      uu.u[3] = (__float_as_uint(y.z) >> 16) | (__float_as_uint(y.w) & 0xFFFF0000u);
      pfrag[kt] = uu.v;
    }

    float pjp0 = 0.f, pjp1 = 0.f, pjp2 = 0.f;
    unsigned char* xo = half ? xr8 : xl8;

    gemm_pass<0>(sm.Ws, Wb, bfl, Wout, xo, N, tid, m, q, half, node, pfrag,
                 pjp0, pjp1, pjp2);
    gemm_pass<1>(sm.Ws, Wb, bfl, Wout, xo, N, tid, m, q, half, node, pfrag,
                 pjp0, pjp1, pjp2);

    if (half == 0) {   // reduce pj over the 4 q-copies of node m
      pjp0 += __shfl_xor(pjp0, 16); pjp0 += __shfl_xor(pjp0, 32);
      pjp1 += __shfl_xor(pjp1, 16); pjp1 += __shfl_xor(pjp1, 32);
      pjp2 += __shfl_xor(pjp2, 16); pjp2 += __shfl_xor(pjp2, 32);
      if (q == 0 && node < N) {
        pj[node * 3 + 0] = pjp0;
        pj[node * 3 + 1] = pjp1;
        pj[node * 3 + 2] = pjp2;
      }
    }
  }
}

// ---- edge: SPLIT blocks per 64-dst bucket; fp8 gathers (no xr staging —
// dst rows are L1-hot), packed-fp16 MLP, LDS partial facc -> pfacc dump.
// bounds(256,5): cap 102 regs vs ~80 used — +25% waves for latency hiding. ----
#define EPG 5
#define GPW 4
#define WCHUNK (EPG * GPW)     // 20 edges per wave iteration
__global__ __launch_bounds__(256, 5) void edge_kernel(
    const uint2* __restrict__ eb,
    const unsigned char* __restrict__ xl8, const unsigned char* __restrict__ xr8,
    const float* __restrict__ pj, const unsigned* __restrict__ weh,
    const unsigned* __restrict__ atth, const unsigned* __restrict__ cur,
    float* __restrict__ pfacc, int N)
{
  __shared__ float facc[64][8];   // [local dst][0..2]=asum, [3..5]=numer
  const int tid  = threadIdx.x;
  const int w    = tid >> 6;
  const int lane = tid & 63;
  const int j = lane / 12;        // edge within group
  const int c = lane % 12;        // 16B chunk within row; head h = c>>2
  const bool act = lane < 60;
  const int cc = act ? c : 0;
  const int blk    = blockIdx.x;
  const int bucket = blk >> 1;    // SPLIT = 2
  const int sl     = blk & 1;
  const int start = bucket * CAP;
  const int end   = (int)cur[bucket * 16];   // start + count

  for (int i = tid; i < 512; i += 256) ((float*)facc)[i] = 0.f;

  union U8 { uint4 u[2]; h2 h[8]; };
  U8 we, at;
  we.u[0] = *(const uint4*)(weh + cc * 8);
  we.u[1] = *(const uint4*)(weh + cc * 8 + 4);
  at.u[0] = *(const uint4*)(atth + cc * 8);
  at.u[1] = *(const uint4*)(atth + cc * 8 + 4);
  const h2 c02 = {(__fp16)0.2f, (__fp16)0.2f};
  __syncthreads();

  const int gw = sl * 4 + w;      // wave-slice id in [0,8)
  const int wstart = start + gw * WCHUNK;
  uint2 rec[GPW];
  #pragma unroll
  for (int g = 0; g < GPW; ++g) {
    int e = wstart + g * EPG + j;
    rec[g] = eb[e < end ? e : start];
  }

  for (int cb = wstart; cb < end; cb += 8 * WCHUNK) {
    int srcs[GPW], dsts[GPW]; float eavs[GPW];
    #pragma unroll
    for (int g = 0; g < GPW; ++g) {
      srcs[g] = (int)(rec[g].x & 0xFFFFu);
      dsts[g] = (int)(rec[g].x >> 16);
      eavs[g] = __uint_as_float(rec[g].y);
    }
    uint4 ul[GPW], ur[GPW]; float pjv[GPW];
    #pragma unroll
    for (int g = 0; g < GPW; ++g)
      ul[g] = *(const uint4*)(xl8 + (size_t)srcs[g] * HCC + cc * 16);
    #pragma unroll
    for (int g = 0; g < GPW; ++g)
      ur[g] = *(const uint4*)(xr8 + (size_t)dsts[g] * HCC + cc * 16);
    #pragma unroll
    for (int g = 0; g < GPW; ++g)
      pjv[g] = pj[srcs[g] * 3 + (c >> 2)];

    // prefetch next iteration's records
    int nxt = cb + 8 * WCHUNK;
    #pragma unroll
    for (int g = 0; g < GPW; ++g) {
      int e = nxt + g * EPG + j;
      rec[g] = eb[(e < end) ? e : start];
    }

    #pragma unroll
    for (int g = 0; g < GPW; ++g) {
      const unsigned* ulp = &ul[g].x;
      const unsigned* urp = &ur[g].x;
      h2 eav2 = __builtin_amdgcn_cvt_pkrtz(eavs[g], eavs[g]);
      float sc = 0.f;
      #pragma unroll
      for (int i = 0; i < 4; ++i) {   // 16 elems: fp8 -> h2 pairs -> pk math
        f32x2 la = __builtin_amdgcn_cvt_pk_f32_fp8(ulp[i], false);
        f32x2 lb = __builtin_amdgcn_cvt_pk_f32_fp8(ulp[i], true);
        f32x2 ra = __builtin_amdgcn_cvt_pk_f32_fp8(urp[i], false);
        f32x2 rb = __builtin_amdgcn_cvt_pk_f32_fp8(urp[i], true);
        h2 l0 = __builtin_amdgcn_cvt_pkrtz(la.x, la.y);
        h2 l1 = __builtin_amdgcn_cvt_pkrtz(lb.x, lb.y);
        h2 r0 = __builtin_amdgcn_cvt_pkrtz(ra.x, ra.y);
        h2 r1 = __builtin_amdgcn_cvt_pkrtz(rb.x, rb.y);
        h2 m0 = l0 + r0 + eav2 * we.h[2 * i];       // 16x-scaled throughout
        h2 m1 = l1 + r1 + eav2 * we.h[2 * i + 1];
        h2 q0 = __builtin_elementwise_max(m0, m0 * c02);  // lrelu(16m)=16*lrelu(m)
        h2 q1 = __builtin_elementwise_max(m1, m1 * c02);
        sc = __builtin_amdgcn_fdot2(q0, at.h[2 * i], sc, false);
        sc = __builtin_amdgcn_fdot2(q1, at.h[2 * i + 1], sc, false);
      }
      sc += __shfl_xor(sc, 1);
      sc += __shfl_xor(sc, 2);
      bool ve = act && (cb + g * EPG + j < end);
      if (ve && (c & 3) == 0) {
        int h = c >> 2;
        int ld = dsts[g] & 63;
        float ex = __expf(sc);   // |a| small: max-free softmax safe
        atomicAdd(&facc[ld][h], ex);
        atomicAdd(&facc[ld][3 + h], ex * pjv[g]);
      }
    }
  }
  __syncthreads();

  for (int i = tid; i < 512; i += 256)      // dump partials (non-atomic)
    pfacc[(size_t)blk * 512 + i] = ((float*)facc)[i];
}

// ---- finalize: merge SPLIT partials, out[n]=exp(score), block sumexp ----
__global__ __launch_bounds__(256) void finalize_kernel(
    const float* __restrict__ pfacc, float* __restrict__ sumexp,
    float* __restrict__ out, int N)
{
  int n = blockIdx.x * 256 + threadIdx.x;
  int t = threadIdx.x;
  float e = 0.f;
  if (n < N) {
    int bucket = n >> 6, ld = n & 63;
    float a0 = 0.f, a1 = 0.f, a2 = 0.f, m0 = 0.f, m1 = 0.f, m2 = 0.f;
    #pragma unroll
    for (int s = 0; s < SPLIT; ++s) {
      const float* p = pfacc + ((size_t)(bucket * SPLIT + s) * 512) + ld * 8;
      a0 += p[0]; a1 += p[1]; a2 += p[2];
      m0 += p[3]; m1 += p[4]; m2 += p[5];
    }
    float accs = 0.f;
    if (a0 > 0.f) accs += m0 / a0;   // empty segment -> 0 (matches ref)
    if (a1 > 0.f) accs += m1 / a1;
    if (a2 > 0.f) accs += m2 / a2;
    e = expf(accs * (1.f / 3.f));
    out[n] = e;
  }
  __shared__ float red[256];
  red[t] = e;
  __syncthreads();
  for (int w = 128; w; w >>= 1) {
    if (t < w) red[t] += red[t + w];
    __syncthreads();
  }
  if (t == 0) atomicAdd(sumexp, red[0]);
}

__global__ __launch_bounds__(256) void norm_kernel(
    float* __restrict__ out, const float* __restrict__ sumexp, int N)
{
  int n = blockIdx.x * 256 + threadIdx.x;
  if (n < N) out[n] /= *sumexp;
}

extern "C" void kernel_launch(void* const* d_in, const int* in_sizes, int n_in,
                              void* d_out, int out_size, void* d_ws, size_t ws_size,
                              hipStream_t stream) {
  const int*   ei   = (const int*)  d_in[0];
  const float* ea   = (const float*)d_in[1];
  const float* pe   = (const float*)d_in[2];
  // d_in[3] sim_w: softmax over 1 element == 1.0 -> unused
  const float* Wl   = (const float*)d_in[4];
  const float* bl   = (const float*)d_in[5];
  const float* Wr   = (const float*)d_in[6];
  const float* br   = (const float*)d_in[7];
  const float* We   = (const float*)d_in[8];
  const float* att  = (const float*)d_in[9];
  // d_in[10] bias_gnn, d_in[12] bout: softmax-invariant constant shift, unused
  const float* Wout = (const float*)d_in[11];

  const int E = in_sizes[0] / 2;
  const int N = in_sizes[2] / EMBC;
  const int NB = (N + 63) >> 6;        // dst buckets of 64
  float* out = (float*)d_out;

  // workspace layout (16B-aligned sections)
  float* ws       = (float*)d_ws;
  float* sumexp   = ws;                               // 1 (+15 pad)
  unsigned* cur   = (unsigned*)(ws + 16);             // NB*16 (64B-padded)
  float* pj       = ws + 16 + (size_t)NB * 16;        // 3N
  float* bfl      = pj + (size_t)3 * N;               // 384
  unsigned* weh   = (unsigned*)(bfl + 384);           // 96
  unsigned* atth  = weh + 96;                         // 96
  bhalf* Wb       = (bhalf*)(atth + 96);              // 384*128 bf16
  unsigned char* xl8 = (unsigned char*)(Wb + (size_t)WCOLS * EMBC);  // N*192 fp8
  unsigned char* xr8 = xl8 + (size_t)N * HCC;                        // N*192 fp8
  uint2* eb       = (uint2*)(xr8 + (size_t)N * HCC);  // NB*CAP*8B bucketed edges
  float* pfacc    = (float*)(eb + (size_t)NB * CAP);  // NB*SPLIT*512 partials

  const int BASE = WCOLS * EMBC;
  const int NSC = (E + SCH - 1) / SCH;
  prep_kernel<<<(BASE + 576 + NB + 1 + 255) / 256, 256, 0, stream>>>(
      Wl, Wr, bl, br, We, att, Wb, bfl, weh, atth, cur, sumexp, NB);
  gemmscatter_kernel<<<NSC + NB * 2, 256, 0, stream>>>(
      pe, Wb, bfl, Wout, xl8, xr8, pj, N, ei, ea, eb, cur, E, NSC);
  edge_kernel<<<NB * SPLIT, 256, 0, stream>>>(eb, xl8, xr8, pj, weh, atth,
                                              cur, pfacc, N);
  finalize_kernel<<<(N + 255) / 256, 256, 0, stream>>>(pfacc, sumexp, out, N);
  norm_kernel<<<(N + 255) / 256, 256, 0, stream>>>(out, sumexp, N);
}

// Round 6
// 185.695 us; speedup vs baseline: 1.1629x; 1.1629x over previous
//
#include <hip/hip_runtime.h>
#include <cfloat>
#include <cmath>

#define NHEADS 3
#define HIDC   64
#define HCC    192   // NHEADS*HIDC
#define EMBC   128
#define WCOLS  384   // 2*HCC (Wl rows ++ Wr rows)
#define CAP    1280  // edge slots per 64-dst bucket (mean 1024, +8 sigma)
#define SCH    4096  // edges per scatter block. Keep blocks (E/SCH=196) <= 256 CUs
                     // (R1: 391 blocks -> serial scatter pairs on some CUs, regressed).
#define SPLIT  2     // edge blocks per bucket (partial facc + finalize)

typedef unsigned short bhalf;
typedef __fp16 half_t;
typedef __attribute__((ext_vector_type(2))) __fp16 h2;
typedef __attribute__((ext_vector_type(8))) short bf16x8;
typedef __attribute__((ext_vector_type(4))) float f32x4;
typedef __attribute__((ext_vector_type(2))) float f32x2;

__device__ __forceinline__ unsigned f2bf(float f) {   // RNE fp32 -> bf16 bits
  unsigned u = __float_as_uint(f);
  return (u + 0x7FFFu + ((u >> 16) & 1u)) >> 16;
}
__device__ __forceinline__ unsigned h2bits(h2 v) {
  union { h2 h; unsigned u; } cv; cv.h = v; return cv.u;
}

// ---- prep: Wb bf16[384][128]; bfl[384]=bl++br; weh=pk16(16*We);
//            atth=pk16(att/16); cur[] bucket cursors; sumexp=0.
// 16x fp8 scale trick: store fp8 of 16*x (leakyrelu positively homogeneous;
// 1/16 folded into atth).
__global__ __launch_bounds__(256) void prep_kernel(
    const float* __restrict__ Wl, const float* __restrict__ Wr,
    const float* __restrict__ bl, const float* __restrict__ br,
    const float* __restrict__ We, const float* __restrict__ att,
    bhalf* __restrict__ Wb, float* __restrict__ bfl,
    unsigned* __restrict__ weh, unsigned* __restrict__ atth,
    unsigned* __restrict__ cur, float* __restrict__ sumexp, int NB)
{
  const int BASE = WCOLS * EMBC;
  int gt = blockIdx.x * 256 + threadIdx.x;
  if (gt < BASE) {                                      // Wb (bf16 RNE)
    int c = gt >> 7, k = gt & 127;
    float v = (c < HCC) ? Wl[c * EMBC + k] : Wr[(c - HCC) * EMBC + k];
    Wb[gt] = (bhalf)f2bf(v);
  } else if (gt < BASE + 384) {                         // bfl = bl++br
    int c = gt - BASE;
    bfl[c] = (c < HCC) ? bl[c] : br[c - HCC];
  } else if (gt < BASE + 480) {                         // weh (96 x fp16x2 of 16*We)
    int i = gt - BASE - 384;
    weh[i] = h2bits(__builtin_amdgcn_cvt_pkrtz(16.f * We[2 * i], 16.f * We[2 * i + 1]));
  } else if (gt < BASE + 576) {                         // atth (att/16)
    int i = gt - BASE - 480;
    atth[i] = h2bits(__builtin_amdgcn_cvt_pkrtz(att[2 * i] * (1.f / 16.f),
                                                att[2 * i + 1] * (1.f / 16.f)));
  } else if (gt < BASE + 576 + NB) {                    // bucket append cursors
    int b = gt - BASE - 576;
    cur[b * 16] = (unsigned)(b * CAP);                  // 64B-padded counters
  } else if (gt == BASE + 576 + NB) {
    *sumexp = 0.f;
  }
}

// One GEMM pass over 6 of the 12 column-tiles, staging ONLY the 96 W rows
// this pass reads (R5 staged all 192 twice = 2x stage traffic, and still
// spilled at the 85-reg cap of bounds(256,6)). Per-pass liveness: acc 24 +
// pfrag 16 + temps ~30 ≈ 70 regs — fits the 102-reg cap of bounds(256,5)
// with ~30 headroom. All register-array indices compile-time (template P,
// scalar pjp0/1/2): dynamic-indexed reg arrays go to scratch.
template<int P>
__device__ __forceinline__ void gemm_pass6(
    bhalf* Ws, const bhalf* __restrict__ Wb, const float* __restrict__ bfl,
    const float* __restrict__ Wout, unsigned char* xo, int N,
    int tid, int m, int q, int half, int node, const bf16x8* pfrag,
    float& pjp0, float& pjp1, float& pjp2)
{
  f32x4 acc[6];
  #pragma unroll
  for (int t = 0; t < 6; ++t) acc[t] = (f32x4){0.f, 0.f, 0.f, 0.f};

  #pragma unroll
  for (int kh = 0; kh < 2; ++kh) {
    __syncthreads();                               // also guards prev-pass reads
    for (int f = tid; f < 96 * 8; f += 256) {      // stage 96 rows x 64-k half
      int cc = f >> 3, s = f & 7;                  // cc in [0,96)
      uint4 v = *(const uint4*)(Wb + (size_t)(half * HCC + P * 96 + cc) * EMBC +
                                kh * 64 + s * 8);
      *(uint4*)(Ws + cc * 64 + ((s ^ (cc & 7)) * 8)) = v;
    }
    __syncthreads();
    #pragma unroll
    for (int kt2 = 0; kt2 < 2; ++kt2) {
      #pragma unroll
      for (int t = 0; t < 6; ++t) {
        bf16x8 wf = *(const bf16x8*)(Ws + (t * 16 + m) * 64 +
                                     (((kt2 << 2) + q) ^ (m & 7)) * 8);
        acc[t] = __builtin_amdgcn_mfma_f32_16x16x32_bf16(wf, pfrag[kh * 2 + kt2],
                                                         acc[t], 0, 0, 0);
      }
    }
  }

  // epilogue for tiles P*6 .. P*6+5
  #pragma unroll
  for (int t = 0; t < 6; ++t) {
    const int tt = P * 6 + t;
    int col = tt * 16 + q * 4;
    float4 b = *(const float4*)(bfl + half * HCC + col);
    float r0 = acc[t][0] + b.x;
    float r1 = acc[t][1] + b.y;
    float r2 = acc[t][2] + b.z;
    float r3 = acc[t][3] + b.w;
    if (half == 0) {
      float4 wo = *(const float4*)(Wout + (tt & 3) * 16 + q * 4);  // L1-hot
      float d = r0 * wo.x + r1 * wo.y + r2 * wo.z + r3 * wo.w;
      if ((tt >> 2) == 0)      pjp0 += d;
      else if ((tt >> 2) == 1) pjp1 += d;
      else                     pjp2 += d;
    }
    if (node < N) {
      int p = 0;
      p = __builtin_amdgcn_cvt_pk_fp8_f32(16.f * r0, 16.f * r1, p, false);
      p = __builtin_amdgcn_cvt_pk_fp8_f32(16.f * r2, 16.f * r3, p, true);
      *(unsigned*)(xo + (size_t)node * HCC + col) = (unsigned)p;
    }
  }
}

// ---- FUSED: edge scatter (blocks < NSC, FIRST so they overlap) + MFMA GEMM.
// gemm: operand swap mfma(Wfrag,pefrag) -> D col=node, row(q*4+reg)=wcol;
// 4 consecutive wcols/lane -> fp8(16x) pack -> direct dword store.
// CONFIG LEDGER (measured):
//   R0: 12-tile + bounds(256,4) = 53.5us (occ 33%, BW 1.47 TB/s). Latency-bound:
//       all pipes <10% busy. Occupancy is THE lever (R3/R5: occ->46%, BW->1.9).
//   R2: direct-global W = 71.6us (LDS bank conflicts measured NON-critical).
//   R3: bounds(256,6)+12-tile = spill (cap 85; VGPR 52->40, +37MB scratch).
//   R5: bounds(256,6)+two-pass full-stage = still spill + 2x stage traffic.
//   R6 (this): bounds(256,5) cap 102 + two-pass 96-row stage (liveness ~70).
// scatter: rank-reuse — phase-1 histogram atomicAdd return IS the rank.
__global__ __launch_bounds__(256, 5) void gemmscatter_kernel(
    const float* __restrict__ pe, const bhalf* __restrict__ Wb,
    const float* __restrict__ bfl, const float* __restrict__ Wout,
    unsigned char* __restrict__ xl8, unsigned char* __restrict__ xr8,
    float* __restrict__ pj, int N,
    const int* __restrict__ ei, const float* __restrict__ ea,
    uint2* __restrict__ eb, unsigned* __restrict__ cur, int E, int NSC)
{
  __shared__ union {
    bhalf Ws[96 * 64];                         // 12288 B gemm W half-tile
    struct { unsigned lh[800]; unsigned lbase[800]; } s;   // 6400 B scatter hists
  } sm;
  const int tid = threadIdx.x;

  if ((int)blockIdx.x < NSC) {   // ============ SCATTER (dispatched first) ============
    const int base = blockIdx.x * SCH;
    for (int i = tid; i < 800; i += 256) sm.s.lh[i] = 0;
    __syncthreads();
    unsigned packed[SCH / 256];     // dst(16b) | rank(<<16), fully in VGPRs
    #pragma unroll
    for (int i = 0; i < SCH / 256; ++i) {
      int e = base + i * 256 + tid;
      packed[i] = 0xFFFFFFFFu;
      if (e < E) {
        unsigned dst = (unsigned)ei[E + e];
        unsigned r = atomicAdd(&sm.s.lh[dst >> 6], 1u);   // rank in bin
        packed[i] = dst | (r << 16);
      }
    }
    __syncthreads();
    for (int i = tid; i < 800; i += 256) {      // reserve global ranges
      unsigned c = sm.s.lh[i];
      sm.s.lbase[i] = c ? atomicAdd(&cur[i * 16], c) : 0u;
    }
    __syncthreads();
    #pragma unroll
    for (int i = 0; i < SCH / 256; ++i) {
      int e = base + i * 256 + tid;
      if (e < E) {
        unsigned pk = packed[i];
        unsigned dst = pk & 0xFFFFu;
        unsigned slot = sm.s.lbase[dst >> 6] + (pk >> 16);
        uint2 rec;
        rec.x = (unsigned)ei[e] | (dst << 16);   // N < 65536
        rec.y = __float_as_uint(ea[e]);
        eb[slot] = rec;
      }
    }
  } else {   // ================= GEMM =================
    const int bid  = blockIdx.x - NSC;
    const int w    = tid >> 6;
    const int lane = tid & 63;
    const int m    = lane & 15;
    const int q    = lane >> 4;
    const int nb   = bid >> 1;
    const int half = bid & 1;
    const int node = nb * 64 + w * 16 + m;
    const size_t prow = (size_t)(node < N ? node : N - 1) * EMBC;

    bf16x8 pfrag[4];
    #pragma unroll
    for (int kt = 0; kt < 4; ++kt) {
      const float* p = pe + prow + kt * 32 + q * 8;
      float4 x = *(const float4*)p;
      float4 y = *(const float4*)(p + 4);
      union { bf16x8 v; unsigned u[4]; } uu;   // trunc-pack pe -> bf16
      uu.u[0] = (__float_as_uint(x.x) >> 16) | (__float_as_uint(x.y) & 0xFFFF0000u);
      uu.u[1] = (__float_as_uint(x.z) >> 16) | (__float_as_uint(x.w) & 0xFFFF0000u);
      uu.u[2] = (__float_as_uint(y.x) >> 16) | (__float_as_uint(y.y) & 0xFFFF0000u);
      uu.u[3] = (__float_as_uint(y.z) >> 16) | (__float_as_uint(y.w) & 0xFFFF0000u);
      pfrag[kt] = uu.v;
    }

    float pjp0 = 0.f, pjp1 = 0.f, pjp2 = 0.f;
    unsigned char* xo = half ? xr8 : xl8;

    gemm_pass6<0>(sm.Ws, Wb, bfl, Wout, xo, N, tid, m, q, half, node, pfrag,
                  pjp0, pjp1, pjp2);
    gemm_pass6<1>(sm.Ws, Wb, bfl, Wout, xo, N, tid, m, q, half, node, pfrag,
                  pjp0, pjp1, pjp2);

    if (half == 0) {   // reduce pj over the 4 q-copies of node m
      pjp0 += __shfl_xor(pjp0, 16); pjp0 += __shfl_xor(pjp0, 32);
      pjp1 += __shfl_xor(pjp1, 16); pjp1 += __shfl_xor(pjp1, 32);
      pjp2 += __shfl_xor(pjp2, 16); pjp2 += __shfl_xor(pjp2, 32);
      if (q == 0 && node < N) {
        pj[node * 3 + 0] = pjp0;
        pj[node * 3 + 1] = pjp1;
        pj[node * 3 + 2] = pjp2;
      }
    }
  }
}

// ---- edge: SPLIT blocks per 64-dst bucket; fp8 gathers (no xr staging —
// dst rows are L1-hot), packed-fp16 MLP, LDS partial facc -> pfacc dump.
// bounds(256,4): known-good; R5's (256,5) change was a confounder, reverted. ----
#define EPG 5
#define GPW 4
#define WCHUNK (EPG * GPW)     // 20 edges per wave iteration
__global__ __launch_bounds__(256, 4) void edge_kernel(
    const uint2* __restrict__ eb,
    const unsigned char* __restrict__ xl8, const unsigned char* __restrict__ xr8,
    const float* __restrict__ pj, const unsigned* __restrict__ weh,
    const unsigned* __restrict__ atth, const unsigned* __restrict__ cur,
    float* __restrict__ pfacc, int N)
{
  __shared__ float facc[64][8];   // [local dst][0..2]=asum, [3..5]=numer
  const int tid  = threadIdx.x;
  const int w    = tid >> 6;
  const int lane = tid & 63;
  const int j = lane / 12;        // edge within group
  const int c = lane % 12;        // 16B chunk within row; head h = c>>2
  const bool act = lane < 60;
  const int cc = act ? c : 0;
  const int blk    = blockIdx.x;
  const int bucket = blk >> 1;    // SPLIT = 2
  const int sl     = blk & 1;
  const int start = bucket * CAP;
  const int end   = (int)cur[bucket * 16];   // start + count

  for (int i = tid; i < 512; i += 256) ((float*)facc)[i] = 0.f;

  union U8 { uint4 u[2]; h2 h[8]; };
  U8 we, at;
  we.u[0] = *(const uint4*)(weh + cc * 8);
  we.u[1] = *(const uint4*)(weh + cc * 8 + 4);
  at.u[0] = *(const uint4*)(atth + cc * 8);
  at.u[1] = *(const uint4*)(atth + cc * 8 + 4);
  const h2 c02 = {(__fp16)0.2f, (__fp16)0.2f};
  __syncthreads();

  const int gw = sl * 4 + w;      // wave-slice id in [0,8)
  const int wstart = start + gw * WCHUNK;
  uint2 rec[GPW];
  #pragma unroll
  for (int g = 0; g < GPW; ++g) {
    int e = wstart + g * EPG + j;
    rec[g] = eb[e < end ? e : start];
  }

  for (int cb = wstart; cb < end; cb += 8 * WCHUNK) {
    int srcs[GPW], dsts[GPW]; float eavs[GPW];
    #pragma unroll
    for (int g = 0; g < GPW; ++g) {
      srcs[g] = (int)(rec[g].x & 0xFFFFu);
      dsts[g] = (int)(rec[g].x >> 16);
      eavs[g] = __uint_as_float(rec[g].y);
    }
    uint4 ul[GPW], ur[GPW]; float pjv[GPW];
    #pragma unroll
    for (int g = 0; g < GPW; ++g)
      ul[g] = *(const uint4*)(xl8 + (size_t)srcs[g] * HCC + cc * 16);
    #pragma unroll
    for (int g = 0; g < GPW; ++g)
      ur[g] = *(const uint4*)(xr8 + (size_t)dsts[g] * HCC + cc * 16);
    #pragma unroll
    for (int g = 0; g < GPW; ++g)
      pjv[g] = pj[srcs[g] * 3 + (c >> 2)];

    // prefetch next iteration's records
    int nxt = cb + 8 * WCHUNK;
    #pragma unroll
    for (int g = 0; g < GPW; ++g) {
      int e = nxt + g * EPG + j;
      rec[g] = eb[(e < end) ? e : start];
    }

    #pragma unroll
    for (int g = 0; g < GPW; ++g) {
      const unsigned* ulp = &ul[g].x;
      const unsigned* urp = &ur[g].x;
      h2 eav2 = __builtin_amdgcn_cvt_pkrtz(eavs[g], eavs[g]);
      float sc = 0.f;
      #pragma unroll
      for (int i = 0; i < 4; ++i) {   // 16 elems: fp8 -> h2 pairs -> pk math
        f32x2 la = __builtin_amdgcn_cvt_pk_f32_fp8(ulp[i], false);
        f32x2 lb = __builtin_amdgcn_cvt_pk_f32_fp8(ulp[i], true);
        f32x2 ra = __builtin_amdgcn_cvt_pk_f32_fp8(urp[i], false);
        f32x2 rb = __builtin_amdgcn_cvt_pk_f32_fp8(urp[i], true);
        h2 l0 = __builtin_amdgcn_cvt_pkrtz(la.x, la.y);
        h2 l1 = __builtin_amdgcn_cvt_pkrtz(lb.x, lb.y);
        h2 r0 = __builtin_amdgcn_cvt_pkrtz(ra.x, ra.y);
        h2 r1 = __builtin_amdgcn_cvt_pkrtz(rb.x, rb.y);
        h2 m0 = l0 + r0 + eav2 * we.h[2 * i];       // 16x-scaled throughout
        h2 m1 = l1 + r1 + eav2 * we.h[2 * i + 1];
        h2 q0 = __builtin_elementwise_max(m0, m0 * c02);  // lrelu(16m)=16*lrelu(m)
        h2 q1 = __builtin_elementwise_max(m1, m1 * c02);
        sc = __builtin_amdgcn_fdot2(q0, at.h[2 * i], sc, false);
        sc = __builtin_amdgcn_fdot2(q1, at.h[2 * i + 1], sc, false);
      }
      sc += __shfl_xor(sc, 1);
      sc += __shfl_xor(sc, 2);
      bool ve = act && (cb + g * EPG + j < end);
      if (ve && (c & 3) == 0) {
        int h = c >> 2;
        int ld = dsts[g] & 63;
        float ex = __expf(sc);   // |a| small: max-free softmax safe
        atomicAdd(&facc[ld][h], ex);
        atomicAdd(&facc[ld][3 + h], ex * pjv[g]);
      }
    }
  }
  __syncthreads();

  for (int i = tid; i < 512; i += 256)      // dump partials (non-atomic)
    pfacc[(size_t)blk * 512 + i] = ((float*)facc)[i];
}

// ---- finalize: merge SPLIT partials, out[n]=exp(score), block sumexp ----
__global__ __launch_bounds__(256) void finalize_kernel(
    const float* __restrict__ pfacc, float* __restrict__ sumexp,
    float* __restrict__ out, int N)
{
  int n = blockIdx.x * 256 + threadIdx.x;
  int t = threadIdx.x;
  float e = 0.f;
  if (n < N) {
    int bucket = n >> 6, ld = n & 63;
    float a0 = 0.f, a1 = 0.f, a2 = 0.f, m0 = 0.f, m1 = 0.f, m2 = 0.f;
    #pragma unroll
    for (int s = 0; s < SPLIT; ++s) {
      const float* p = pfacc + ((size_t)(bucket * SPLIT + s) * 512) + ld * 8;
      a0 += p[0]; a1 += p[1]; a2 += p[2];
      m0 += p[3]; m1 += p[4]; m2 += p[5];
    }
    float accs = 0.f;
    if (a0 > 0.f) accs += m0 / a0;   // empty segment -> 0 (matches ref)
    if (a1 > 0.f) accs += m1 / a1;
    if (a2 > 0.f) accs += m2 / a2;
    e = expf(accs * (1.f / 3.f));
    out[n] = e;
  }
  __shared__ float red[256];
  red[t] = e;
  __syncthreads();
  for (int w = 128; w; w >>= 1) {
    if (t < w) red[t] += red[t + w];
    __syncthreads();
  }
  if (t == 0) atomicAdd(sumexp, red[0]);
}

__global__ __launch_bounds__(256) void norm_kernel(
    float* __restrict__ out, const float* __restrict__ sumexp, int N)
{
  int n = blockIdx.x * 256 + threadIdx.x;
  if (n < N) out[n] /= *sumexp;
}

extern "C" void kernel_launch(void* const* d_in, const int* in_sizes, int n_in,
                              void* d_out, int out_size, void* d_ws, size_t ws_size,
                              hipStream_t stream) {
  const int*   ei   = (const int*)  d_in[0];
  const float* ea   = (const float*)d_in[1];
  const float* pe   = (const float*)d_in[2];
  // d_in[3] sim_w: softmax over 1 element == 1.0 -> unused
  const float* Wl   = (const float*)d_in[4];
  const float* bl   = (const float*)d_in[5];
  const float* Wr   = (const float*)d_in[6];
  const float* br   = (const float*)d_in[7];
  const float* We   = (const float*)d_in[8];
  const float* att  = (const float*)d_in[9];
  // d_in[10] bias_gnn, d_in[12] bout: softmax-invariant constant shift, unused
  const float* Wout = (const float*)d_in[11];

  const int E = in_sizes[0] / 2;
  const int N = in_sizes[2] / EMBC;
  const int NB = (N + 63) >> 6;        // dst buckets of 64
  float* out = (float*)d_out;

  // workspace layout (16B-aligned sections)
  float* ws       = (float*)d_ws;
  float* sumexp   = ws;                               // 1 (+15 pad)
  unsigned* cur   = (unsigned*)(ws + 16);             // NB*16 (64B-padded)
  float* pj       = ws + 16 + (size_t)NB * 16;        // 3N
  float* bfl      = pj + (size_t)3 * N;               // 384
  unsigned* weh   = (unsigned*)(bfl + 384);           // 96
  unsigned* atth  = weh + 96;                         // 96
  bhalf* Wb       = (bhalf*)(atth + 96);              // 384*128 bf16
  unsigned char* xl8 = (unsigned char*)(Wb + (size_t)WCOLS * EMBC);  // N*192 fp8
  unsigned char* xr8 = xl8 + (size_t)N * HCC;                        // N*192 fp8
  uint2* eb       = (uint2*)(xr8 + (size_t)N * HCC);  // NB*CAP*8B bucketed edges
  float* pfacc    = (float*)(eb + (size_t)NB * CAP);  // NB*SPLIT*512 partials

  const int BASE = WCOLS * EMBC;
  const int NSC = (E + SCH - 1) / SCH;
  prep_kernel<<<(BASE + 576 + NB + 1 + 255) / 256, 256, 0, stream>>>(
      Wl, Wr, bl, br, We, att, Wb, bfl, weh, atth, cur, sumexp, NB);
  gemmscatter_kernel<<<NSC + NB * 2, 256, 0, stream>>>(
      pe, Wb, bfl, Wout, xl8, xr8, pj, N, ei, ea, eb, cur, E, NSC);
  edge_kernel<<<NB * SPLIT, 256, 0, stream>>>(eb, xl8, xr8, pj, weh, atth,
                                              cur, pfacc, N);
  finalize_kernel<<<(N + 255) / 256, 256, 0, stream>>>(pfacc, sumexp, out, N);
  norm_kernel<<<(N + 255) / 256, 256, 0, stream>>>(out, sumexp, N);
}